// Round 14
// baseline (861.697 us; speedup 1.0000x reference)
//
#include <hip/hip_runtime.h>
#include <stdint.h>

// Fused Swin window-attention, MI355X gfx950.  v13 = v12 (= v8 + setprio,
// 210us) restructured to 2 windows per block (paired at stride 2048 so both
// share the same mask-window -> window 2's table+weights are L1/L2-warm).
// Both x tiles staged up-front (64 KB LDS) -> window 2 pays no staging stall.
// Window loop is '#pragma unroll 1': bodies strictly sequential, registers
// reused -> v8's register peak preserved (v9/v10/v11 spill trap avoided).

#define WN 49      // tokens per window
#define CD 256     // channels
#define NH 8       // heads

typedef float    f32x4  __attribute__((ext_vector_type(4)));
typedef _Float16 half8  __attribute__((ext_vector_type(8)));
typedef _Float16 half4  __attribute__((ext_vector_type(4)));
typedef __fp16   fp16x2 __attribute__((ext_vector_type(2)));

#define MFMA32H(a,b,c) __builtin_amdgcn_mfma_f32_16x16x32_f16((a),(b),(c),0,0,0)
#define PRIO1() __builtin_amdgcn_s_setprio(1)
#define PRIO0() __builtin_amdgcn_s_setprio(0)

__device__ __forceinline__ unsigned pkh(float a, float b) {
  fp16x2 h = __builtin_amdgcn_cvt_pkrtz(a, b);
  union { fp16x2 h; unsigned u; } c; c.h = h; return c.u;
}
__device__ __forceinline__ half4 cvt4(f32x4 v) {
  union { unsigned u[2]; half4 h; } c;
  c.u[0] = pkh(v[0], v[1]);
  c.u[1] = pkh(v[2], v[3]);
  return c.h;
}
__device__ __forceinline__ half8 cat8(half4 a, half4 b) {
  return __builtin_shufflevector(a, b, 0, 1, 2, 3, 4, 5, 6, 7);
}

// ---------------- workspace layout (bytes) ----------------
// WQKV : [8 h][8 kk][6 fb][64 lane][8 f16]  fragment-major qkv_w,
//        K-fragments (fb 2,3) pre-scaled by hd^-0.5*log2e        = 393216
// WPROJ: [8 kk][16 fb][64 lane][8 f16]      fragment-major proj_w = 131072
// TBL  : [64 mw][8 h][4 it][4 jt][64 lane] float4 = S-acc C-init
//        (bias+mask)*log2e, j>=49 -> -21640                       = 8388608
#define WS_WQKV  0
#define WS_WPROJ 393216
#define WS_TBL   524288

__global__ __launch_bounds__(256) void prep_kernel(
    const float* __restrict__ qkv_w, const float* __restrict__ proj_w,
    const float* __restrict__ rpb,   const int*   __restrict__ relidx,
    const float* __restrict__ mask,
    _Float16* __restrict__ wqkv, _Float16* __restrict__ wproj,
    float* __restrict__ tblw)
{
  const float kscale = 0.17677669529663687f * 1.4426950408889634f;
  int t = blockIdx.x * blockDim.x + threadIdx.x;
  if (t < 8*8*6*64) {                      // qkv_w fragments, head-grouped rows
    int l    = t & 63;
    int fb   = (t >> 6) % 6;
    int rest = t / (64*6);
    int kk = rest & 7, h = rest >> 3;
    int rbase = (fb < 2) ? (h*32 + fb*16)
              : (fb < 4) ? (256 + h*32 + (fb-2)*16)
                         : (512 + h*32 + (fb-4)*16);
    float sc = (fb == 2 || fb == 3) ? kscale : 1.0f;
    int row = rbase + (l & 15);
    int col = kk*32 + (l >> 4)*8;
    const float* src = qkv_w + row*CD + col;
    _Float16* dst = wqkv + (size_t)t*8;
    #pragma unroll
    for (int j2 = 0; j2 < 8; ++j2) dst[j2] = (_Float16)(src[j2] * sc);
  }
  if (t < 8*16*64) {                       // proj_w fragments
    int l  = t & 63;
    int fb = (t >> 6) & 15;
    int kk = t >> 10;
    int row = fb*16 + (l & 15);
    int col = kk*32 + (l >> 4)*8;
    const float* src = proj_w + row*CD + col;
    _Float16* dst = wproj + (size_t)t*8;
    #pragma unroll
    for (int j2 = 0; j2 < 8; ++j2) dst[j2] = (_Float16)src[j2];
  }
  if (t < 64*8*4*4*64) {                   // S-acc C-init table, frag-major
    int l  = t & 63;
    int jt = (t >> 6) & 3;
    int it = (t >> 8) & 3;
    int h  = (t >> 10) & 7;
    int mw = t >> 13;
    int i  = it*16 + (l & 15);
    int ii = i < WN ? i : WN - 1;          // padded query cols: copy row 48
    float4 v;
    #pragma unroll
    for (int e = 0; e < 4; ++e) {
      int j = jt*16 + (l >> 4)*4 + e;
      float val = -21640.0f;               // padded keys: exp2 -> 0
      if (j < WN)
        val = (rpb[relidx[ii*WN + j]*NH + h] + mask[mw*WN*WN + ii*WN + j])
              * 1.4426950408889634f;
      ((float*)&v)[e] = val;
    }
    ((float4*)tblw)[t] = v;
  }
}

// LDS: 64 KB = 2 x 32 KB window tiles.  Per tile: phase 1 x f16 [64][256]
// (byte-swizzle ^((row&7)<<4)); phase 2 (after barrier) O f16, same swizzle.
__global__ __launch_bounds__(512, 4) void wattn_fused(
    const float* __restrict__ x,
    const float* __restrict__ qkvb,
    const float* __restrict__ projb,
    const _Float16* __restrict__ wqkv,
    const _Float16* __restrict__ wproj,
    const float* __restrict__ tbl,
    float* __restrict__ out)
{
  __shared__ char smem[65536] __attribute__((aligned(16)));
  const int tid = threadIdx.x;
  const int w  = tid >> 6;     // wave = head
  const int l  = tid & 63;
  const int lg = l >> 4;
  const int ll = l & 15;
  const int blk = blockIdx.x;  // windows blk and blk+2048 (same mask-window)
  const int xsw = (ll & 7) << 4;
  const f32x4 Z4 = {0.f, 0.f, 0.f, 0.f};

  // ---- stage BOTH x tiles (fp32 -> f16, swizzled), rows 49..63 zeroed ----
  {
    int row = tid >> 3, seg = tid & 7;
    int cb = seg*64;
    int sw = (row & 7) << 4;
    #pragma unroll
    for (int ww = 0; ww < 2; ++ww) {
      char* dst = smem + ww*32768 + row*512;
      if (row < WN) {
        const float4* s4 = (const float4*)(x + (size_t)(blk + ww*2048)*WN*CD
                                             + row*CD + seg*32);
        #pragma unroll
        for (int q = 0; q < 4; ++q) {
          int c = (q + seg) & 3;
          float4 a = s4[2*c], b = s4[2*c+1];
          uint4 u;
          u.x = pkh(a.x, a.y); u.y = pkh(a.z, a.w);
          u.z = pkh(b.x, b.y); u.w = pkh(b.z, b.w);
          *(uint4*)(dst + ((cb + c*16) ^ sw)) = u;
        }
      } else {
        uint4 z = {0u,0u,0u,0u};
        #pragma unroll
        for (int q = 0; q < 4; ++q) *(uint4*)(dst + ((cb + q*16) ^ sw)) = z;
      }
    }
  }
  __syncthreads();

  const uint4* wsrc = (const uint4*)wqkv + (size_t)(w*8)*384 + l;  // +kk*384+fb*64
  const float kscale = 0.17677669529663687f * 1.4426950408889634f;

  #pragma unroll 1
  for (int ww = 0; ww < 2; ++ww) {
    char* sm = smem + ww*32768;
    const int wid = blk + ww*2048;

    // ---- qkv pass 1: Q^T, K^T (channel-major); acc init = bias ----
    f32x4 aq[2][4], ak[2][4];
    #pragma unroll
    for (int ds = 0; ds < 2; ++ds) {
      f32x4 bq = *(const f32x4*)(qkvb + w*32 + ds*16 + lg*4);
      f32x4 bk = *(const f32x4*)(qkvb + 256 + w*32 + ds*16 + lg*4);
      #pragma unroll
      for (int e = 0; e < 4; ++e) bk[e] *= kscale;
      #pragma unroll
      for (int tt = 0; tt < 4; ++tt) { aq[ds][tt] = bq; ak[ds][tt] = bk; }
    }

    #pragma unroll 2
    for (int kk = 0; kk < 8; ++kk) {
      uint4 wb[4];
      #pragma unroll
      for (int fb = 0; fb < 4; ++fb) wb[fb] = wsrc[kk*384 + fb*64];
      half8 xf[4];
      #pragma unroll
      for (int tt = 0; tt < 4; ++tt)
        xf[tt] = *(const half8*)(sm + (tt*16 + ll)*512 + ((kk*64 + lg*16) ^ xsw));
      half8 wq0 = *(const half8*)&wb[0], wq1 = *(const half8*)&wb[1];
      half8 wk0 = *(const half8*)&wb[2], wk1 = *(const half8*)&wb[3];
      PRIO1();
      #pragma unroll
      for (int tt = 0; tt < 4; ++tt) {
        aq[0][tt] = MFMA32H(wq0, xf[tt], aq[0][tt]);
        aq[1][tt] = MFMA32H(wq1, xf[tt], aq[1][tt]);
        ak[0][tt] = MFMA32H(wk0, xf[tt], ak[0][tt]);
        ak[1][tt] = MFMA32H(wk1, xf[tt], ak[1][tt]);
      }
      PRIO0();
    }

    // cvt + concat to K=32 frags (consistent k-perm on both operands)
    half8 qcat[4], kcat[4];
    #pragma unroll
    for (int tt = 0; tt < 4; ++tt) {
      qcat[tt] = cat8(cvt4(aq[0][tt]), cvt4(aq[1][tt]));
      kcat[tt] = cat8(cvt4(ak[0][tt]), cvt4(ak[1][tt]));
    }

    // ---- S^T = K * Q^T (64x64); acc init = (bias+mask)*log2e table ----
    f32x4 st[4][4];
    {
      const f32x4* tb = (const f32x4*)tbl + ((size_t)((wid & 63)*8 + w) << 10) + l;
      #pragma unroll
      for (int it = 0; it < 4; ++it)
        #pragma unroll
        for (int jt = 0; jt < 4; ++jt)
          st[jt][it] = tb[(it*4 + jt)*64];
    }
    PRIO1();
    #pragma unroll
    for (int jt = 0; jt < 4; ++jt)
      #pragma unroll
      for (int it = 0; it < 4; ++it)
        st[jt][it] = MFMA32H(kcat[jt], qcat[it], st[jt][it]);
    PRIO0();

    // early-issue kk=0 V weights: latency hides under softmax
    uint4 vw0 = wsrc[4*64];
    uint4 vw1 = wsrc[5*64];

    // ---- softmax: p = exp2(st) ----
    #pragma unroll
    for (int jt = 0; jt < 4; ++jt)
      #pragma unroll
      for (int it = 0; it < 4; ++it)
        #pragma unroll
        for (int r = 0; r < 4; ++r)
          st[jt][it][r] = __builtin_amdgcn_exp2f(st[jt][it][r]);

    // ---- row sums + normalize + cvt -> P concat frags ----
    half8 pcat[2][4];          // [j-half][it]
    #pragma unroll
    for (int it = 0; it < 4; ++it) {
      float s = 0.f;
      #pragma unroll
      for (int jt = 0; jt < 4; ++jt)
        #pragma unroll
        for (int r = 0; r < 4; ++r) s += st[jt][it][r];
      s += __shfl_xor(s, 16);
      s += __shfl_xor(s, 32);
      float inv = 1.0f / s;
      f32x4 p[4];
      #pragma unroll
      for (int jt = 0; jt < 4; ++jt)
        #pragma unroll
        for (int r = 0; r < 4; ++r) p[jt][r] = st[jt][it][r] * inv;
      pcat[0][it] = cat8(cvt4(p[0]), cvt4(p[1]));
      pcat[1][it] = cat8(cvt4(p[2]), cvt4(p[3]));
    }

    // ---- qkv pass 2: V (token-major), acc init 0; kk=0 peeled ----
    f32x4 av[4][2];
    #pragma unroll
    for (int a = 0; a < 4; ++a) { av[a][0] = Z4; av[a][1] = Z4; }
    {
      half8 wv0 = *(const half8*)&vw0, wv1 = *(const half8*)&vw1;
      half8 xf[4];
      #pragma unroll
      for (int tt = 0; tt < 4; ++tt)
        xf[tt] = *(const half8*)(sm + (tt*16 + ll)*512 + ((lg*16) ^ xsw));
      PRIO1();
      #pragma unroll
      for (int tt = 0; tt < 4; ++tt) {
        av[tt][0] = MFMA32H(xf[tt], wv0, av[tt][0]);
        av[tt][1] = MFMA32H(xf[tt], wv1, av[tt][1]);
      }
      PRIO0();
    }
    #pragma unroll 2
    for (int kk = 1; kk < 8; ++kk) {
      uint4 wb0 = wsrc[kk*384 + 4*64];
      uint4 wb1 = wsrc[kk*384 + 5*64];
      half8 xf[4];
      #pragma unroll
      for (int tt = 0; tt < 4; ++tt)
        xf[tt] = *(const half8*)(sm + (tt*16 + ll)*512 + ((kk*64 + lg*16) ^ xsw));
      half8 wv0 = *(const half8*)&wb0, wv1 = *(const half8*)&wb1;
      PRIO1();
      #pragma unroll
      for (int tt = 0; tt < 4; ++tt) {
        av[tt][0] = MFMA32H(xf[tt], wv0, av[tt][0]);
        av[tt][1] = MFMA32H(xf[tt], wv1, av[tt][1]);
      }
      PRIO0();
    }
    half8 vcat[2][2];          // [dt][j-half]
    #pragma unroll
    for (int dt = 0; dt < 2; ++dt) {
      vcat[dt][0] = cat8(cvt4(av[0][dt]), cvt4(av[1][dt]));
      vcat[dt][1] = cat8(cvt4(av[2][dt]), cvt4(av[3][dt]));
    }

    // ---- PV: O^T = V^T * P (K=32 over tokens, 2 halves) ----
    f32x4 ot[2][4];
    #pragma unroll
    for (int a = 0; a < 2; ++a)
      #pragma unroll
      for (int b = 0; b < 4; ++b) ot[a][b] = Z4;
    PRIO1();
    #pragma unroll
    for (int dt = 0; dt < 2; ++dt)
      #pragma unroll
      for (int it = 0; it < 4; ++it) {
        ot[dt][it] = MFMA32H(vcat[dt][0], pcat[0][it], ot[dt][it]);
        ot[dt][it] = MFMA32H(vcat[dt][1], pcat[1][it], ot[dt][it]);
      }
    PRIO0();

    // early-issue kk=0 proj weights
    const uint4* psrc = (const uint4*)wproj + l;   // + (kk*16+fb)*64
    uint4 pw0 = psrc[(2*w)*64];
    uint4 pw1 = psrc[(2*w + 1)*64];

    __syncthreads();   // all x[ww] reads done -> region reusable as O

    // ---- write O [i][c] f16 (swz), + v-bias (rows of P sum to 1) ----
    {
      f32x4 bv[2];
      #pragma unroll
      for (int dt = 0; dt < 2; ++dt)
        bv[dt] = *(const f32x4*)(qkvb + 512 + w*32 + dt*16 + lg*4);
      #pragma unroll
      for (int it = 0; it < 4; ++it) {
        int i = it*16 + ll;
        int isw = (i & 7) << 4;
        #pragma unroll
        for (int dt = 0; dt < 2; ++dt) {
          int c0 = w*32 + dt*16 + lg*4;
          uint2 u;
          u.x = pkh(ot[dt][it][0] + bv[dt][0], ot[dt][it][1] + bv[dt][1]);
          u.y = pkh(ot[dt][it][2] + bv[dt][2], ot[dt][it][3] + bv[dt][3]);
          *(uint2*)(sm + i*512 + ((c0*2) ^ isw)) = u;
        }
      }
    }
    __syncthreads();

    // ---- proj GEMM: acc init = proj bias; kk=0 peeled ----
    f32x4 ap[4][2];
    {
      float pb0 = projb[w*32 + ll], pb1 = projb[w*32 + 16 + ll];
      f32x4 i0 = {pb0, pb0, pb0, pb0};
      f32x4 i1 = {pb1, pb1, pb1, pb1};
      #pragma unroll
      for (int a = 0; a < 4; ++a) { ap[a][0] = i0; ap[a][1] = i1; }
    }
    {
      half8 bfr0 = *(const half8*)&pw0;
      half8 bfr1 = *(const half8*)&pw1;
      half8 af[4];
      #pragma unroll
      for (int mt = 0; mt < 4; ++mt) {
        int i = mt*16 + ll;
        af[mt] = *(const half8*)(sm + ((i*512 + lg*16) ^ ((i & 7) << 4)));
      }
      PRIO1();
      #pragma unroll
      for (int mt = 0; mt < 4; ++mt) {
        ap[mt][0] = MFMA32H(af[mt], bfr0, ap[mt][0]);
        ap[mt][1] = MFMA32H(af[mt], bfr1, ap[mt][1]);
      }
      PRIO0();
    }
    #pragma unroll 2
    for (int kk = 1; kk < 8; ++kk) {
      uint4 pb0 = psrc[(kk*16 + 2*w)*64];
      uint4 pb1 = psrc[(kk*16 + 2*w + 1)*64];
      half8 bfr0 = *(const half8*)&pb0;
      half8 bfr1 = *(const half8*)&pb1;
      half8 af[4];
      #pragma unroll
      for (int mt = 0; mt < 4; ++mt) {
        int i = mt*16 + ll;
        af[mt] = *(const half8*)(sm + ((i*512 + kk*64 + lg*16) ^ ((i & 7) << 4)));
      }
      PRIO1();
      #pragma unroll
      for (int mt = 0; mt < 4; ++mt) {
        ap[mt][0] = MFMA32H(af[mt], bfr0, ap[mt][0]);
        ap[mt][1] = MFMA32H(af[mt], bfr1, ap[mt][1]);
      }
      PRIO0();
    }

    float* op = out + (size_t)wid*WN*CD;
    #pragma unroll
    for (int mt = 0; mt < 4; ++mt)
      #pragma unroll
      for (int r = 0; r < 4; ++r) {
        int i = mt*16 + lg*4 + r;
        if (i < WN) {
          op[i*CD + w*32 + ll]      = ap[mt][0][r];
          op[i*CD + w*32 + 16 + ll] = ap[mt][1][r];
        }
      }
  }
}

extern "C" void kernel_launch(void* const* d_in, const int* in_sizes, int n_in,
                              void* d_out, int out_size, void* d_ws, size_t ws_size,
                              hipStream_t stream) {
  const float* x      = (const float*)d_in[0];
  const float* mask   = (const float*)d_in[1];
  const float* qkv_w  = (const float*)d_in[2];
  const float* qkv_b  = (const float*)d_in[3];
  const float* proj_w = (const float*)d_in[4];
  const float* proj_b = (const float*)d_in[5];
  const float* rpb    = (const float*)d_in[6];
  const int*   relidx = (const int*)d_in[7];

  char* ws = (char*)d_ws;
  _Float16* wqkv  = (_Float16*)(ws + WS_WQKV);
  _Float16* wproj = (_Float16*)(ws + WS_WPROJ);
  float*    tblw  = (float*)(ws + WS_TBL);
  float* out = (float*)d_out;

  prep_kernel<<<2048, 256, 0, stream>>>(qkv_w, proj_w, rpb, relidx, mask,
                                        wqkv, wproj, tblw);
  wattn_fused<<<2048, 512, 0, stream>>>(x, qkv_b, proj_b, wqkv, wproj,
                                        tblw, out);
}

// Round 15
// 209.130 us; speedup vs baseline: 4.1204x; 4.1204x over previous
//
#include <hip/hip_runtime.h>
#include <stdint.h>

// Fused Swin window-attention, MI355X gfx950.  v14 = v12 (= v8 + setprio,
// best: 210.7us) with O moved to a SEPARATE 32 KB LDS region (total 64 KB):
// the pre-O-write barrier (which protected x from being overwritten) is
// deleted -> 3 barriers/block -> 2.  Pure LDS-addressing change: register
// pressure and dataflow are byte-identical to v12 (v9-v13 all spilled on
// anything more).  2 blocks/CU unchanged (128 KB of 160 KB LDS).

#define WN 49      // tokens per window
#define CD 256     // channels
#define NH 8       // heads

typedef float    f32x4  __attribute__((ext_vector_type(4)));
typedef _Float16 half8  __attribute__((ext_vector_type(8)));
typedef _Float16 half4  __attribute__((ext_vector_type(4)));
typedef __fp16   fp16x2 __attribute__((ext_vector_type(2)));

#define MFMA32H(a,b,c) __builtin_amdgcn_mfma_f32_16x16x32_f16((a),(b),(c),0,0,0)
#define PRIO1() __builtin_amdgcn_s_setprio(1)
#define PRIO0() __builtin_amdgcn_s_setprio(0)

__device__ __forceinline__ unsigned pkh(float a, float b) {
  fp16x2 h = __builtin_amdgcn_cvt_pkrtz(a, b);
  union { fp16x2 h; unsigned u; } c; c.h = h; return c.u;
}
__device__ __forceinline__ half4 cvt4(f32x4 v) {
  union { unsigned u[2]; half4 h; } c;
  c.u[0] = pkh(v[0], v[1]);
  c.u[1] = pkh(v[2], v[3]);
  return c.h;
}
__device__ __forceinline__ half8 cat8(half4 a, half4 b) {
  return __builtin_shufflevector(a, b, 0, 1, 2, 3, 4, 5, 6, 7);
}

// ---------------- workspace layout (bytes) ----------------
// WQKV : [8 h][8 kk][6 fb][64 lane][8 f16]  fragment-major qkv_w,
//        K-fragments (fb 2,3) pre-scaled by hd^-0.5*log2e        = 393216
// WPROJ: [8 kk][16 fb][64 lane][8 f16]      fragment-major proj_w = 131072
// TBL  : [64 mw][8 h][4 it][4 jt][64 lane] float4 = S-acc C-init
//        (bias+mask)*log2e, j>=49 -> -21640                       = 8388608
#define WS_WQKV  0
#define WS_WPROJ 393216
#define WS_TBL   524288

__global__ __launch_bounds__(256) void prep_kernel(
    const float* __restrict__ qkv_w, const float* __restrict__ proj_w,
    const float* __restrict__ rpb,   const int*   __restrict__ relidx,
    const float* __restrict__ mask,
    _Float16* __restrict__ wqkv, _Float16* __restrict__ wproj,
    float* __restrict__ tblw)
{
  const float kscale = 0.17677669529663687f * 1.4426950408889634f;
  int t = blockIdx.x * blockDim.x + threadIdx.x;
  if (t < 8*8*6*64) {                      // qkv_w fragments, head-grouped rows
    int l    = t & 63;
    int fb   = (t >> 6) % 6;
    int rest = t / (64*6);
    int kk = rest & 7, h = rest >> 3;
    int rbase = (fb < 2) ? (h*32 + fb*16)
              : (fb < 4) ? (256 + h*32 + (fb-2)*16)
                         : (512 + h*32 + (fb-4)*16);
    float sc = (fb == 2 || fb == 3) ? kscale : 1.0f;
    int row = rbase + (l & 15);
    int col = kk*32 + (l >> 4)*8;
    const float* src = qkv_w + row*CD + col;
    _Float16* dst = wqkv + (size_t)t*8;
    #pragma unroll
    for (int j2 = 0; j2 < 8; ++j2) dst[j2] = (_Float16)(src[j2] * sc);
  }
  if (t < 8*16*64) {                       // proj_w fragments
    int l  = t & 63;
    int fb = (t >> 6) & 15;
    int kk = t >> 10;
    int row = fb*16 + (l & 15);
    int col = kk*32 + (l >> 4)*8;
    const float* src = proj_w + row*CD + col;
    _Float16* dst = wproj + (size_t)t*8;
    #pragma unroll
    for (int j2 = 0; j2 < 8; ++j2) dst[j2] = (_Float16)src[j2];
  }
  if (t < 64*8*4*4*64) {                   // S-acc C-init table, frag-major
    int l  = t & 63;
    int jt = (t >> 6) & 3;
    int it = (t >> 8) & 3;
    int h  = (t >> 10) & 7;
    int mw = t >> 13;
    int i  = it*16 + (l & 15);
    int ii = i < WN ? i : WN - 1;          // padded query cols: copy row 48
    float4 v;
    #pragma unroll
    for (int e = 0; e < 4; ++e) {
      int j = jt*16 + (l >> 4)*4 + e;
      float val = -21640.0f;               // padded keys: exp2 -> 0
      if (j < WN)
        val = (rpb[relidx[ii*WN + j]*NH + h] + mask[mw*WN*WN + ii*WN + j])
              * 1.4426950408889634f;
      ((float*)&v)[e] = val;
    }
    ((float4*)tblw)[t] = v;
  }
}

// LDS: 64 KB.  [0,32K): x f16 [64 tok][256 ch], byte-swizzle ^((row&7)<<4).
//              [32K,64K): O f16 [64 tok][256 ch], same swizzle (separate
//              region -> no barrier needed between PV and O-write).
__global__ __launch_bounds__(512, 4) void wattn_fused(
    const float* __restrict__ x,
    const float* __restrict__ qkvb,
    const float* __restrict__ projb,
    const _Float16* __restrict__ wqkv,
    const _Float16* __restrict__ wproj,
    const float* __restrict__ tbl,
    float* __restrict__ out)
{
  __shared__ char smem[65536] __attribute__((aligned(16)));
  char* om = smem + 32768;     // O region
  const int tid = threadIdx.x;
  const int w  = tid >> 6;     // wave = head
  const int l  = tid & 63;
  const int lg = l >> 4;
  const int ll = l & 15;
  const int blk = blockIdx.x;
  const int xsw = (ll & 7) << 4;
  const f32x4 Z4 = {0.f, 0.f, 0.f, 0.f};

  // ---- stage x (fp32 -> f16, swizzled), rows 49..63 zeroed ----
  // chunk rotation c=(q+seg)&3: spreads same-row lanes across bank slots.
  {
    int row = tid >> 3, seg = tid & 7;
    char* dst = smem + row*512;
    int cb = seg*64;
    int sw = (row & 7) << 4;
    if (row < WN) {
      const float4* s4 = (const float4*)(x + (size_t)blk*WN*CD + row*CD + seg*32);
      #pragma unroll
      for (int q = 0; q < 4; ++q) {
        int c = (q + seg) & 3;
        float4 a = s4[2*c], b = s4[2*c+1];
        uint4 u;
        u.x = pkh(a.x, a.y); u.y = pkh(a.z, a.w);
        u.z = pkh(b.x, b.y); u.w = pkh(b.z, b.w);
        *(uint4*)(dst + ((cb + c*16) ^ sw)) = u;
      }
    } else {
      uint4 z = {0u,0u,0u,0u};
      #pragma unroll
      for (int q = 0; q < 4; ++q) *(uint4*)(dst + ((cb + q*16) ^ sw)) = z;
    }
  }
  __syncthreads();

  const uint4* wsrc = (const uint4*)wqkv + (size_t)(w*8)*384 + l;  // +kk*384+fb*64

  // ---- qkv pass 1: Q^T, K^T (channel-major); acc init = bias ----
  // acc: col(lane&15)=token, row((lane>>4)*4+r)=out-channel within 16-tile.
  const float kscale = 0.17677669529663687f * 1.4426950408889634f;
  f32x4 aq[2][4], ak[2][4];
  #pragma unroll
  for (int ds = 0; ds < 2; ++ds) {
    f32x4 bq = *(const f32x4*)(qkvb + w*32 + ds*16 + lg*4);
    f32x4 bk = *(const f32x4*)(qkvb + 256 + w*32 + ds*16 + lg*4);
    #pragma unroll
    for (int e = 0; e < 4; ++e) bk[e] *= kscale;
    #pragma unroll
    for (int tt = 0; tt < 4; ++tt) { aq[ds][tt] = bq; ak[ds][tt] = bk; }
  }

  #pragma unroll 2
  for (int kk = 0; kk < 8; ++kk) {
    uint4 wb[4];
    #pragma unroll
    for (int fb = 0; fb < 4; ++fb) wb[fb] = wsrc[kk*384 + fb*64];
    half8 xf[4];
    #pragma unroll
    for (int tt = 0; tt < 4; ++tt)
      xf[tt] = *(const half8*)(smem + (tt*16 + ll)*512 + ((kk*64 + lg*16) ^ xsw));
    half8 wq0 = *(const half8*)&wb[0], wq1 = *(const half8*)&wb[1];
    half8 wk0 = *(const half8*)&wb[2], wk1 = *(const half8*)&wb[3];
    PRIO1();
    #pragma unroll
    for (int tt = 0; tt < 4; ++tt) {
      aq[0][tt] = MFMA32H(wq0, xf[tt], aq[0][tt]);
      aq[1][tt] = MFMA32H(wq1, xf[tt], aq[1][tt]);
      ak[0][tt] = MFMA32H(wk0, xf[tt], ak[0][tt]);
      ak[1][tt] = MFMA32H(wk1, xf[tt], ak[1][tt]);
    }
    PRIO0();
  }

  // cvt + concat to K=32 frags: elem e<4 from ds=0 tile, e>=4 from ds=1.
  // Both S operands carry the same (group,elem)->channel map -> S correct.
  half8 qcat[4], kcat[4];
  #pragma unroll
  for (int tt = 0; tt < 4; ++tt) {
    qcat[tt] = cat8(cvt4(aq[0][tt]), cvt4(aq[1][tt]));
    kcat[tt] = cat8(cvt4(ak[0][tt]), cvt4(ak[1][tt]));
  }

  // ---- S^T = K * Q^T (64x64); acc init = (bias+mask)*log2e table ----
  f32x4 st[4][4];
  {
    const f32x4* tb = (const f32x4*)tbl + ((size_t)((blk & 63)*8 + w) << 10) + l;
    #pragma unroll
    for (int it = 0; it < 4; ++it)
      #pragma unroll
      for (int jt = 0; jt < 4; ++jt)
        st[jt][it] = tb[(it*4 + jt)*64];
  }
  PRIO1();
  #pragma unroll
  for (int jt = 0; jt < 4; ++jt)
    #pragma unroll
    for (int it = 0; it < 4; ++it)
      st[jt][it] = MFMA32H(kcat[jt], qcat[it], st[jt][it]);
  PRIO0();

  // early-issue kk=0 V weights: latency hides under softmax
  uint4 vw0 = wsrc[4*64];
  uint4 vw1 = wsrc[5*64];

  // ---- softmax: p = exp2(st) (table pre-scaled by log2e; no max-sub) ----
  #pragma unroll
  for (int jt = 0; jt < 4; ++jt)
    #pragma unroll
    for (int it = 0; it < 4; ++it)
      #pragma unroll
      for (int r = 0; r < 4; ++r)
        st[jt][it][r] = __builtin_amdgcn_exp2f(st[jt][it][r]);

  // ---- row sums + normalize + cvt -> P concat frags (PV B-operand) ----
  half8 pcat[2][4];          // [j-half][it]
  #pragma unroll
  for (int it = 0; it < 4; ++it) {
    float s = 0.f;
    #pragma unroll
    for (int jt = 0; jt < 4; ++jt)
      #pragma unroll
      for (int r = 0; r < 4; ++r) s += st[jt][it][r];
    s += __shfl_xor(s, 16);
    s += __shfl_xor(s, 32);
    float inv = 1.0f / s;
    f32x4 p[4];
    #pragma unroll
    for (int jt = 0; jt < 4; ++jt)
      #pragma unroll
      for (int r = 0; r < 4; ++r) p[jt][r] = st[jt][it][r] * inv;
    pcat[0][it] = cat8(cvt4(p[0]), cvt4(p[1]));
    pcat[1][it] = cat8(cvt4(p[2]), cvt4(p[3]));
  }

  // ---- qkv pass 2: V (token-major), acc init 0; kk=0 peeled (early loads) ----
  f32x4 av[4][2];
  #pragma unroll
  for (int a = 0; a < 4; ++a) { av[a][0] = Z4; av[a][1] = Z4; }
  {
    half8 wv0 = *(const half8*)&vw0, wv1 = *(const half8*)&vw1;
    half8 xf[4];
    #pragma unroll
    for (int tt = 0; tt < 4; ++tt)
      xf[tt] = *(const half8*)(smem + (tt*16 + ll)*512 + ((lg*16) ^ xsw));
    PRIO1();
    #pragma unroll
    for (int tt = 0; tt < 4; ++tt) {
      av[tt][0] = MFMA32H(xf[tt], wv0, av[tt][0]);
      av[tt][1] = MFMA32H(xf[tt], wv1, av[tt][1]);
    }
    PRIO0();
  }
  #pragma unroll 2
  for (int kk = 1; kk < 8; ++kk) {
    uint4 wb0 = wsrc[kk*384 + 4*64];
    uint4 wb1 = wsrc[kk*384 + 5*64];
    half8 xf[4];
    #pragma unroll
    for (int tt = 0; tt < 4; ++tt)
      xf[tt] = *(const half8*)(smem + (tt*16 + ll)*512 + ((kk*64 + lg*16) ^ xsw));
    half8 wv0 = *(const half8*)&wb0, wv1 = *(const half8*)&wb1;
    PRIO1();
    #pragma unroll
    for (int tt = 0; tt < 4; ++tt) {
      av[tt][0] = MFMA32H(xf[tt], wv0, av[tt][0]);
      av[tt][1] = MFMA32H(xf[tt], wv1, av[tt][1]);
    }
    PRIO0();
  }
  // V^T concat frags (PV A-operand): same (group,elem)->token map as pcat.
  half8 vcat[2][2];          // [dt][j-half]
  #pragma unroll
  for (int dt = 0; dt < 2; ++dt) {
    vcat[dt][0] = cat8(cvt4(av[0][dt]), cvt4(av[1][dt]));
    vcat[dt][1] = cat8(cvt4(av[2][dt]), cvt4(av[3][dt]));
  }

  // ---- PV: O^T = V^T * P (K=32 over tokens, 2 halves) ----
  f32x4 ot[2][4];
  #pragma unroll
  for (int a = 0; a < 2; ++a)
    #pragma unroll
    for (int b = 0; b < 4; ++b) ot[a][b] = Z4;
  PRIO1();
  #pragma unroll
  for (int dt = 0; dt < 2; ++dt)
    #pragma unroll
    for (int it = 0; it < 4; ++it) {
      ot[dt][it] = MFMA32H(vcat[dt][0], pcat[0][it], ot[dt][it]);
      ot[dt][it] = MFMA32H(vcat[dt][1], pcat[1][it], ot[dt][it]);
    }
  PRIO0();

  // early-issue kk=0 proj weights (flows freely: no barrier until O done)
  const uint4* psrc = (const uint4*)wproj + l;     // + (kk*16+fb)*64
  uint4 pw0 = psrc[(2*w)*64];
  uint4 pw1 = psrc[(2*w + 1)*64];

  // ---- write O [i][c] f16 to SEPARATE region (swz (i&7)<<4), + v-bias ----
  // (no barrier needed: O region disjoint from x region)
  {
    f32x4 bv[2];
    #pragma unroll
    for (int dt = 0; dt < 2; ++dt)
      bv[dt] = *(const f32x4*)(qkvb + 512 + w*32 + dt*16 + lg*4);
    #pragma unroll
    for (int it = 0; it < 4; ++it) {
      int i = it*16 + ll;
      int isw = (i & 7) << 4;
      #pragma unroll
      for (int dt = 0; dt < 2; ++dt) {
        int c0 = w*32 + dt*16 + lg*4;
        uint2 u;
        u.x = pkh(ot[dt][it][0] + bv[dt][0], ot[dt][it][1] + bv[dt][1]);
        u.y = pkh(ot[dt][it][2] + bv[dt][2], ot[dt][it][3] + bv[dt][3]);
        *(uint2*)(om + i*512 + ((c0*2) ^ isw)) = u;
      }
    }
  }
  __syncthreads();   // all O writes visible -> proj can read cross-wave cols

  // ---- proj GEMM: out = O @ proj_w^T; acc init = proj bias; kk=0 peeled ----
  f32x4 ap[4][2];
  {
    float pb0 = projb[w*32 + ll], pb1 = projb[w*32 + 16 + ll];
    f32x4 i0 = {pb0, pb0, pb0, pb0};
    f32x4 i1 = {pb1, pb1, pb1, pb1};
    #pragma unroll
    for (int a = 0; a < 4; ++a) { ap[a][0] = i0; ap[a][1] = i1; }
  }
  {
    half8 bfr0 = *(const half8*)&pw0;
    half8 bfr1 = *(const half8*)&pw1;
    half8 af[4];
    #pragma unroll
    for (int mt = 0; mt < 4; ++mt) {
      int i = mt*16 + ll;
      af[mt] = *(const half8*)(om + ((i*512 + lg*16) ^ ((i & 7) << 4)));
    }
    PRIO1();
    #pragma unroll
    for (int mt = 0; mt < 4; ++mt) {
      ap[mt][0] = MFMA32H(af[mt], bfr0, ap[mt][0]);
      ap[mt][1] = MFMA32H(af[mt], bfr1, ap[mt][1]);
    }
    PRIO0();
  }
  #pragma unroll 2
  for (int kk = 1; kk < 8; ++kk) {
    uint4 pb0 = psrc[(kk*16 + 2*w)*64];
    uint4 pb1 = psrc[(kk*16 + 2*w + 1)*64];
    half8 bfr0 = *(const half8*)&pb0;
    half8 bfr1 = *(const half8*)&pb1;
    half8 af[4];
    #pragma unroll
    for (int mt = 0; mt < 4; ++mt) {
      int i = mt*16 + ll;
      af[mt] = *(const half8*)(om + ((i*512 + kk*64 + lg*16) ^ ((i & 7) << 4)));
    }
    PRIO1();
    #pragma unroll
    for (int mt = 0; mt < 4; ++mt) {
      ap[mt][0] = MFMA32H(af[mt], bfr0, ap[mt][0]);
      ap[mt][1] = MFMA32H(af[mt], bfr1, ap[mt][1]);
    }
    PRIO0();
  }

  float* op = out + (size_t)blk*WN*CD;
  #pragma unroll
  for (int mt = 0; mt < 4; ++mt)
    #pragma unroll
    for (int r = 0; r < 4; ++r) {
      int i = mt*16 + lg*4 + r;
      if (i < WN) {
        op[i*CD + w*32 + ll]      = ap[mt][0][r];
        op[i*CD + w*32 + 16 + ll] = ap[mt][1][r];
      }
    }
}

extern "C" void kernel_launch(void* const* d_in, const int* in_sizes, int n_in,
                              void* d_out, int out_size, void* d_ws, size_t ws_size,
                              hipStream_t stream) {
  const float* x      = (const float*)d_in[0];
  const float* mask   = (const float*)d_in[1];
  const float* qkv_w  = (const float*)d_in[2];
  const float* qkv_b  = (const float*)d_in[3];
  const float* proj_w = (const float*)d_in[4];
  const float* proj_b = (const float*)d_in[5];
  const float* rpb    = (const float*)d_in[6];
  const int*   relidx = (const int*)d_in[7];

  char* ws = (char*)d_ws;
  _Float16* wqkv  = (_Float16*)(ws + WS_WQKV);
  _Float16* wproj = (_Float16*)(ws + WS_WPROJ);
  float*    tblw  = (float*)(ws + WS_TBL);
  float* out = (float*)d_out;

  prep_kernel<<<2048, 256, 0, stream>>>(qkv_w, proj_w, rpb, relidx, mask,
                                        wqkv, wproj, tblw);
  wattn_fused<<<4096, 512, 0, stream>>>(x, qkv_b, proj_b, wqkv, wproj,
                                        tblw, out);
}